// Round 1
// baseline (628448.926 us; speedup 1.0000x reference)
//
#include <hip/hip_runtime.h>
#include <hip/hip_cooperative_groups.h>
#include <cmath>

namespace cg = cooperative_groups;

#define VOCAB   4096
#define ENC_DIM 1024
#define PRED_H  640
#define JOINT_H 640
#define TMAX    128
#define MAX_SYM 30
#define NSTEPS  (TMAX*(MAX_SYM+1))   // 3968
#define NWG     256
#define NTHR    256

__device__ __forceinline__ float wave_red(float v){
  v += __shfl_xor(v, 32, 64);
  v += __shfl_xor(v, 16, 64);
  v += __shfl_xor(v,  8, 64);
  v += __shfl_xor(v,  4, 64);
  v += __shfl_xor(v,  2, 64);
  v += __shfl_xor(v,  1, 64);
  return v;
}

__device__ __forceinline__ float sigf(float x){ return 1.0f/(1.0f+expf(-x)); }

// One LSTM cell phase: this WG computes output elements [eb,ee).
// wave w computes gate w (torch order i,f,g,o -> rows w*640+j).
__device__ __forceinline__ void lstm_phase(int wave, int lane, int tid, int eb, int ee,
    const float* __restrict__ Wih, const float* __restrict__ Whh, const float* __restrict__ bias,
    const float* x,          // may be nullptr => zero input
    const float* hcur, const float* ccur,
    float* hout, float* cout, float* zsh)
{
  for (int j = eb; j < ee; ++j){
    const float* wi = Wih + (size_t)(wave*PRED_H + j)*PRED_H;
    const float* wh = Whh + (size_t)(wave*PRED_H + j)*PRED_H;
    float acc = 0.0f;
    if (x){
      for (int c = lane; c < PRED_H; c += 64) acc = fmaf(wi[c], x[c], acc);
    }
    for (int c = lane; c < PRED_H; c += 64) acc = fmaf(wh[c], hcur[c], acc);
    acc = wave_red(acc);
    if (lane == 0) zsh[wave] = acc + bias[wave*PRED_H + j];
    __syncthreads();
    if (tid == 0){
      float ig = sigf(zsh[0]);
      float fg = sigf(zsh[1]);
      float gg = tanhf(zsh[2]);
      float og = sigf(zsh[3]);
      float c2 = fg*ccur[j] + ig*gg;
      cout[j] = c2;
      hout[j] = og*tanhf(c2);
    }
    __syncthreads();
  }
}

__global__ __launch_bounds__(NTHR)
void rnnt_decode(const float* __restrict__ enc,
                 const int*   __restrict__ outlen_p,
                 const float* __restrict__ emb,
                 const float* __restrict__ Wih0, const float* __restrict__ Whh0, const float* __restrict__ b0,
                 const float* __restrict__ Wih1, const float* __restrict__ Whh1, const float* __restrict__ b1,
                 const float* __restrict__ Wj1,  const float* __restrict__ bj1,
                 const float* __restrict__ Wj2,  const float* __restrict__ bj2,
                 float* __restrict__ out,
                 unsigned long long* __restrict__ amax,  // [2]
                 float* __restrict__ bufs,               // [2][4][PRED_H]  (h0,c0,h1,c1)
                 float* __restrict__ hid)                // [JOINT_H]
{
  cg::grid_group grid = cg::this_grid();
  const int wg = blockIdx.x, tid = threadIdx.x;
  const int wave = tid >> 6, lane = tid & 63;
  const int timesteps = outlen_p[0];

  __shared__ float zsh[4];
  __shared__ unsigned long long psh[4];
  __shared__ int ksh;

  // ---- init (every call: ws is not re-poisoned between replays) ----
  if (tid < 10) bufs[wg*10 + tid] = 0.0f;   // zero state set 0 (4*640 floats)
  if (wg == 0 && tid == 0){
    __hip_atomic_store(&amax[0], 0ull, __ATOMIC_RELAXED, __HIP_MEMORY_SCOPE_AGENT);
    __hip_atomic_store(&amax[1], 0ull, __ATOMIC_RELAXED, __HIP_MEMORY_SCOPE_AGENT);
  }
  grid.sync();

  int curb = 0, t = 0, sa = 0, last = -1, cnt = 0;
  bool done = false;

  const int eb = (wg*PRED_H)/NWG, ee = ((wg+1)*PRED_H)/NWG;   // 2-3 elems per WG

  for (int s = 0; s < NSTEPS; ++s){
    if (!done){
      float* cur  = bufs + (size_t)curb*(4*PRED_H);
      float* prop = bufs + (size_t)(curb^1)*(4*PRED_H);

      // ---- Phase A: LSTM layer 0 ----
      {
        const float* x = (last < 0) ? nullptr : (emb + (size_t)last*PRED_H);
        lstm_phase(wave, lane, tid, eb, ee, Wih0, Whh0, b0,
                   x, cur /*h0*/, cur + PRED_H /*c0*/,
                   prop /*h0n*/, prop + PRED_H /*c0n*/, zsh);
      }
      grid.sync();
      // recycle the argmax cell used two steps from now (all readers are past it)
      if (s >= 1 && wg == 0 && tid == 0)
        __hip_atomic_store(&amax[(s-1)&1], 0ull, __ATOMIC_RELAXED, __HIP_MEMORY_SCOPE_AGENT);

      // ---- Phase B: LSTM layer 1 (input = h0n always) ----
      lstm_phase(wave, lane, tid, eb, ee, Wih1, Whh1, b1,
                 prop /*h0n*/, cur + 2*PRED_H /*h1*/, cur + 3*PRED_H /*c1*/,
                 prop + 2*PRED_H /*h1n*/, prop + 3*PRED_H /*c1n*/, zsh);
      grid.sync();

      // ---- Phase C: joint hidden = relu(Wj1 @ [f; h1n] + bj1) ----
      {
        const int tcap = (t < TMAX-1) ? t : (TMAX-1);
        const float* f   = enc + (size_t)tcap*ENC_DIM;
        const float* h1n = prop + 2*PRED_H;
        for (int r = eb; r < ee; ++r){
          const float* wr = Wj1 + (size_t)r*(ENC_DIM+PRED_H);
          float acc = 0.0f;
          for (int c = tid; c < ENC_DIM; c += NTHR) acc = fmaf(wr[c],         f[c],   acc);
          for (int c = tid; c < PRED_H;  c += NTHR) acc = fmaf(wr[ENC_DIM+c], h1n[c], acc);
          acc = wave_red(acc);
          if (lane == 0) zsh[wave] = acc;
          __syncthreads();
          if (tid == 0){
            float v = zsh[0]+zsh[1]+zsh[2]+zsh[3] + bj1[r];
            hid[r] = v > 0.0f ? v : 0.0f;
          }
          __syncthreads();
        }
      }
      grid.sync();

      // ---- Phase D: logits (16 per WG) + packed atomicMax argmax ----
      {
        unsigned long long best = 0ull;
        for (int q = 0; q < 4; ++q){
          int r = wg*16 + wave*4 + q;
          const float* wr = Wj2 + (size_t)r*JOINT_H;
          float acc = 0.0f;
          for (int c = lane; c < JOINT_H; c += 64) acc = fmaf(wr[c], hid[c], acc);
          acc = wave_red(acc);
          if (lane == 0){
            float lg = acc + bj2[r];
            out[(size_t)s*VOCAB + r] = lg;           // real logits (done==false here)
            unsigned u = __float_as_uint(lg);
            u = (u & 0x80000000u) ? ~u : (u | 0x80000000u);   // order-preserving map
            unsigned long long p = ((unsigned long long)u << 32)
                                 | (unsigned long long)(0xFFFFFFFFu - (unsigned)r); // ties -> smallest idx
            if (p > best) best = p;
          }
        }
        if (lane == 0) psh[wave] = best;
        __syncthreads();
        if (tid == 0){
          unsigned long long m = psh[0];
          if (psh[1] > m) m = psh[1];
          if (psh[2] > m) m = psh[2];
          if (psh[3] > m) m = psh[3];
          atomicMax(&amax[s&1], m);
        }
      }
      grid.sync();

      // ---- Phase E: read winner, update scalar state redundantly in every WG ----
      if (tid == 0){
        unsigned long long v = __hip_atomic_load(&amax[s&1], __ATOMIC_RELAXED, __HIP_MEMORY_SCOPE_AGENT);
        ksh = (int)(0xFFFFFFFFu - (unsigned)(v & 0xFFFFFFFFull));
      }
      __syncthreads();
      int k = ksh;
      __syncthreads();
      bool stop = (k == 0) || (sa >= MAX_SYM);
      if (!stop){                      // emit
        if (wg == 0 && tid == 0) out[(size_t)NSTEPS*VOCAB + cnt] = (float)k;
        cnt++; sa++; last = k; curb ^= 1;   // keep proposed hidden state
      } else {                         // blank / max-sym: advance time, discard proposal
        sa = 0; t++;
        if (t >= timesteps) done = true;
      }
    } else {
      // post-done steps: reference outputs zeros
      if (tid < 16) out[(size_t)s*VOCAB + wg*16 + tid] = 0.0f;
    }
  }

  // labels tail (-1) and cnt
  int g = wg*NTHR + tid;
  for (int i = cnt + g; i < NSTEPS; i += NWG*NTHR)
    out[(size_t)NSTEPS*VOCAB + i] = -1.0f;
  if (wg == 0 && tid == 0)
    out[(size_t)NSTEPS*VOCAB + NSTEPS] = (float)cnt;
}

extern "C" void kernel_launch(void* const* d_in, const int* in_sizes, int n_in,
                              void* d_out, int out_size, void* d_ws, size_t ws_size,
                              hipStream_t stream) {
  const float* enc  = (const float*)d_in[0];
  const int*   olen = (const int*)  d_in[1];
  const float* emb  = (const float*)d_in[2];
  const float* Wih0 = (const float*)d_in[3];
  const float* Whh0 = (const float*)d_in[4];
  const float* b0   = (const float*)d_in[5];
  const float* Wih1 = (const float*)d_in[6];
  const float* Whh1 = (const float*)d_in[7];
  const float* b1   = (const float*)d_in[8];
  const float* Wj1  = (const float*)d_in[9];
  const float* bj1  = (const float*)d_in[10];
  const float* Wj2  = (const float*)d_in[11];
  const float* bj2  = (const float*)d_in[12];
  float* out = (float*)d_out;

  unsigned long long* amax = (unsigned long long*)d_ws;
  float* bufs = (float*)((char*)d_ws + 64);
  float* hid  = bufs + 2*4*PRED_H;

  void* args[] = {&enc,&olen,&emb,&Wih0,&Whh0,&b0,&Wih1,&Whh1,&b1,
                  &Wj1,&bj1,&Wj2,&bj2,&out,&amax,&bufs,&hid};
  hipLaunchCooperativeKernel((const void*)rnnt_decode, dim3(NWG), dim3(NTHR),
                             args, 0, stream);
}

// Round 3
// 100956.500 us; speedup vs baseline: 6.2249x; 6.2249x over previous
//
#include <hip/hip_runtime.h>
#include <cmath>

#define VOCAB   4096
#define ENC_DIM 1024
#define PRED_H  640
#define JOINT_H 640
#define TMAX    128
#define MAX_SYM 30
#define NSTEPS  (TMAX*(MAX_SYM+1))   // 3968
#define NWG     256
#define NTHR    512
#define RLX __ATOMIC_RELAXED
#define AGT __HIP_MEMORY_SCOPE_AGENT

// ws layout (bytes):
//   0     : cnt1[32 groups], group g at word g*16 (64B-line separated)  (2048B)
//   2048  : cnt2 (level-2 counter)
//   2112  : flag (value: (epoch<<12)|k)
//   2176  : amax[2] (u64)
//   2240  : bufs: 2 x [h0(640) | h1(640)] floats   (10240B)
//   12480 : hid[640] floats                        (2560B)  -> ends 15040

__device__ __forceinline__ float wave_red(float v){
  v += __shfl_xor(v, 32, 64);
  v += __shfl_xor(v, 16, 64);
  v += __shfl_xor(v,  8, 64);
  v += __shfl_xor(v,  4, 64);
  v += __shfl_xor(v,  2, 64);
  v += __shfl_xor(v,  1, 64);
  return v;
}

__device__ __forceinline__ float sigf(float x){ return 1.0f/(1.0f+expf(-x)); }

__device__ __forceinline__ unsigned long long packlg(float lg, int r){
  unsigned u = __float_as_uint(lg);
  u = (u & 0x80000000u) ? ~u : (u | 0x80000000u);   // order-preserving
  return ((unsigned long long)u << 32) | (unsigned long long)(0xFFFFFFFFu - (unsigned)r);
}

// Two-level epoch barrier: 32 groups x 8 WGs. Relaxed agent atomics only —
// data visibility is provided by sc-coherent (atomic relaxed agent) data ops
// + per-wave s_waitcnt vmcnt(0) before arrival. withK: last arriver folds the
// argmax result into the release flag.
__device__ __forceinline__ unsigned gbar(unsigned* ws, unsigned ep, int withK,
                                         unsigned long long* amax, int slot,
                                         int tid, int wg, int* ksh_p){
  asm volatile("s_waitcnt vmcnt(0)" ::: "memory");   // my wave's coherent stores done
  __syncthreads();                                   // all waves of WG done
  if (tid == 0){
    unsigned g = (unsigned)wg >> 3;
    unsigned o = __hip_atomic_fetch_add(&ws[g*16], 1u, RLX, AGT);
    if (o == ep*8u + 7u){
      unsigned o2 = __hip_atomic_fetch_add(&ws[512], 1u, RLX, AGT);
      if (o2 == ep*32u + 31u){
        unsigned kk = 0u;
        if (withK){
          unsigned long long v = __hip_atomic_load(&amax[slot], RLX, AGT);
          kk = 0xFFFFFFFFu - (unsigned)(v & 0xFFFFFFFFull);
        }
        __hip_atomic_store(&ws[528], ((ep+1u)<<12) | kk, RLX, AGT);
      }
    }
    unsigned f;
    while (((f = __hip_atomic_load(&ws[528], RLX, AGT)) >> 12) < ep + 1u){
      __builtin_amdgcn_s_sleep(1);
    }
    *ksh_p = (int)(f & 0xFFFu);
  }
  __syncthreads();
  return ep + 1u;
}

__global__ void init_ws(unsigned* ws){
  for (int i = threadIdx.x; i < 4096; i += 256) ws[i] = 0u;   // 16 KB
}

__global__ __launch_bounds__(NTHR, 2)
void rnnt_decode(const float* __restrict__ enc,
                 const int*   __restrict__ outlen_p,
                 const float* __restrict__ emb,
                 const float* __restrict__ Wih0, const float* __restrict__ Whh0, const float* __restrict__ b0,
                 const float* __restrict__ Wih1, const float* __restrict__ Whh1, const float* __restrict__ b1,
                 const float* __restrict__ Wj1,  const float* __restrict__ bj1,
                 const float* __restrict__ Wj2,  const float* __restrict__ bj2,
                 float* __restrict__ out,
                 unsigned* __restrict__ wsb,
                 unsigned long long* __restrict__ amax,
                 float* __restrict__ bufs,
                 float* __restrict__ hid)
{
  const int wg = blockIdx.x, tid = threadIdx.x;
  const int wave = tid >> 6, lane = tid & 63;
  const int timesteps = outlen_p[0];

  __shared__ float xsh[ENC_DIM];          // emb-x / h0n / enc-frame
  __shared__ float hsh[PRED_H];           // h-vector / hid
  __shared__ float zsh[4][4];             // LSTM gate partials (4 gates x <=3 j)
  __shared__ float zjs[8];                // phase-C wave partials
  __shared__ float c0c[4], c1c[4], c0p[4], c1p[4];
  __shared__ unsigned long long psh[8];
  __shared__ int ksh;

  // ragged ownership (identical to round-1): j-elems [jb,je)
  const int jb = (wg*PRED_H)/NWG;
  const int je = ((wg+1)*PRED_H)/NWG;
  const int nj = je - jb;                 // 2 or 3

  // ---- persistent weight registers (loaded once) ----
  // LSTM rows: ri -> (gate = ri&3, j = ri>>2); wave handles ri=wave and ri=wave+8.
  const int riA = wave, riB = wave + 8;
  const int gA = riA & 3, jA = riA >> 2;
  const int gB = riB & 3, jBx = riB >> 2;
  const bool hasB = (riB < 4*nj);
  const int rowA = gA*PRED_H + jb + jA;
  const int rowB = hasB ? (gB*PRED_H + jb + jBx) : 0;

  float w0xA[10], w0hA[10], w0xB[10], w0hB[10];
  float w1xA[10], w1hA[10], w1xB[10], w1hB[10];
  #pragma unroll
  for (int i = 0; i < 10; ++i){
    int c = lane + (i<<6);
    w0xA[i] = Wih0[(size_t)rowA*PRED_H + c];
    w0hA[i] = Whh0[(size_t)rowA*PRED_H + c];
    w1xA[i] = Wih1[(size_t)rowA*PRED_H + c];
    w1hA[i] = Whh1[(size_t)rowA*PRED_H + c];
    w0xB[i] = hasB ? Wih0[(size_t)rowB*PRED_H + c] : 0.f;
    w0hB[i] = hasB ? Whh0[(size_t)rowB*PRED_H + c] : 0.f;
    w1xB[i] = hasB ? Wih1[(size_t)rowB*PRED_H + c] : 0.f;
    w1hB[i] = hasB ? Whh1[(size_t)rowB*PRED_H + c] : 0.f;
  }
  const float bA0 = b0[rowA], bA1 = b1[rowA];
  const float bB0 = hasB ? b0[rowB] : 0.f, bB1 = hasB ? b1[rowB] : 0.f;

  // Wj1: rows jb..jb+nj, 256-thread-strided cols (replicates round-1 order)
  float wj1f[3][4], wj1h[3][3];
  #pragma unroll
  for (int rr = 0; rr < 3; ++rr){
    #pragma unroll
    for (int i = 0; i < 4; ++i) wj1f[rr][i] = 0.f;
    #pragma unroll
    for (int i = 0; i < 3; ++i) wj1h[rr][i] = 0.f;
    if (rr < nj && tid < 256){
      int r = jb + rr;
      #pragma unroll
      for (int i = 0; i < 4; ++i)
        wj1f[rr][i] = Wj1[(size_t)r*(ENC_DIM+PRED_H) + tid + (i<<8)];
      #pragma unroll
      for (int i = 0; i < 3; ++i){
        int c = tid + (i<<8);
        wj1h[rr][i] = (c < PRED_H) ? Wj1[(size_t)r*(ENC_DIM+PRED_H) + ENC_DIM + c] : 0.f;
      }
    }
  }

  // Wj2: 16 rows per WG, 2 per wave
  const int rA2 = wg*16 + wave*2, rB2 = rA2 + 1;
  float wj2A[10], wj2B[10];
  #pragma unroll
  for (int i = 0; i < 10; ++i){
    int c = lane + (i<<6);
    wj2A[i] = Wj2[(size_t)rA2*JOINT_H + c];
    wj2B[i] = Wj2[(size_t)rB2*JOINT_H + c];
  }
  const float bjA2 = bj2[rA2], bjB2 = bj2[rB2];

  if (tid < 4){ c0c[tid] = 0.f; c1c[tid] = 0.f; }

  unsigned ep = 0;
  int curb = 0, t = 0, sa = 0, last = -1, cnt = 0;
  bool done = false;

  for (int s = 0; s < NSTEPS; ++s){
    if (done){
      if (wg < 8) out[(size_t)s*VOCAB + wg*NTHR + tid] = 0.f;
      continue;
    }
    float* hc = bufs + curb*(2*PRED_H);
    float* hp = bufs + (curb^1)*(2*PRED_H);

    // ===== A: LSTM layer 0 =====
    for (int i = tid; i < PRED_H; i += NTHR){                 // FULL 640 coverage
      hsh[i] = __hip_atomic_load(&hc[i], RLX, AGT);
      xsh[i] = (last >= 0) ? emb[(size_t)last*PRED_H + i] : 0.f;
    }
    __syncthreads();
    {
      float acc = 0.f;
      #pragma unroll
      for (int i = 0; i < 10; ++i) acc = fmaf(w0xA[i], xsh[lane+(i<<6)], acc);
      #pragma unroll
      for (int i = 0; i < 10; ++i) acc = fmaf(w0hA[i], hsh[lane+(i<<6)], acc);
      acc = wave_red(acc);
      if (lane == 0) zsh[gA][jA] = acc + bA0;
      if (hasB){
        float a2 = 0.f;
        #pragma unroll
        for (int i = 0; i < 10; ++i) a2 = fmaf(w0xB[i], xsh[lane+(i<<6)], a2);
        #pragma unroll
        for (int i = 0; i < 10; ++i) a2 = fmaf(w0hB[i], hsh[lane+(i<<6)], a2);
        a2 = wave_red(a2);
        if (lane == 0) zsh[gB][jBx] = a2 + bB0;
      }
    }
    __syncthreads();
    if (tid < nj){
      float ig = sigf(zsh[0][tid]), fg = sigf(zsh[1][tid]);
      float gg = tanhf(zsh[2][tid]), og = sigf(zsh[3][tid]);
      float c2 = fg*c0c[tid] + ig*gg;
      c0p[tid] = c2;
      __hip_atomic_store(&hp[jb+tid], og*tanhf(c2), RLX, AGT);
    }
    ep = gbar(wsb, ep, 0, amax, 0, tid, wg, &ksh);

    // ===== B: LSTM layer 1 =====
    for (int i = tid; i < PRED_H; i += NTHR){                 // FULL 640 coverage
      xsh[i] = __hip_atomic_load(&hp[i], RLX, AGT);           // h0n
      hsh[i] = __hip_atomic_load(&hc[PRED_H+i], RLX, AGT);    // h1
    }
    __syncthreads();
    {
      float acc = 0.f;
      #pragma unroll
      for (int i = 0; i < 10; ++i) acc = fmaf(w1xA[i], xsh[lane+(i<<6)], acc);
      #pragma unroll
      for (int i = 0; i < 10; ++i) acc = fmaf(w1hA[i], hsh[lane+(i<<6)], acc);
      acc = wave_red(acc);
      if (lane == 0) zsh[gA][jA] = acc + bA1;
      if (hasB){
        float a2 = 0.f;
        #pragma unroll
        for (int i = 0; i < 10; ++i) a2 = fmaf(w1xB[i], xsh[lane+(i<<6)], a2);
        #pragma unroll
        for (int i = 0; i < 10; ++i) a2 = fmaf(w1hB[i], hsh[lane+(i<<6)], a2);
        a2 = wave_red(a2);
        if (lane == 0) zsh[gB][jBx] = a2 + bB1;
      }
    }
    __syncthreads();
    if (tid < nj){
      float ig = sigf(zsh[0][tid]), fg = sigf(zsh[1][tid]);
      float gg = tanhf(zsh[2][tid]), og = sigf(zsh[3][tid]);
      float c2 = fg*c1c[tid] + ig*gg;
      c1p[tid] = c2;
      __hip_atomic_store(&hp[PRED_H+jb+tid], og*tanhf(c2), RLX, AGT);
    }
    ep = gbar(wsb, ep, 0, amax, 0, tid, wg, &ksh);

    // ===== C: joint hidden (replicates round-1 256-thread-strided order) =====
    {
      int tcap = (t < TMAX-1) ? t : (TMAX-1);
      for (int i = tid; i < PRED_H; i += NTHR)                // FULL 640
        hsh[i] = __hip_atomic_load(&hp[PRED_H+i], RLX, AGT);  // h1n
      for (int i = tid; i < ENC_DIM; i += NTHR)               // FULL 1024
        xsh[i] = enc[(size_t)tcap*ENC_DIM + i];               // f (read-only)
      __syncthreads();
      #pragma unroll
      for (int rr = 0; rr < 3; ++rr){
        if (rr < nj){
          if (tid < 256){
            float acc = 0.f;
            #pragma unroll
            for (int i = 0; i < 4; ++i) acc = fmaf(wj1f[rr][i], xsh[tid+(i<<8)], acc);
            #pragma unroll
            for (int i = 0; i < 3; ++i){
              int c = tid + (i<<8);
              acc = fmaf(wj1h[rr][i], hsh[(c < PRED_H) ? c : 0], acc);
            }
            acc = wave_red(acc);
            if (lane == 0) zjs[wave] = acc;
          }
          __syncthreads();
          if (tid == 0){
            float v = zjs[0] + zjs[1] + zjs[2] + zjs[3] + bj1[jb+rr];
            v = v > 0.f ? v : 0.f;
            __hip_atomic_store(&hid[jb+rr], v, RLX, AGT);
          }
          __syncthreads();
        }
      }
    }
    ep = gbar(wsb, ep, 0, amax, 0, tid, wg, &ksh);
    if (wg == 0 && tid == 0)                               // recycle next step's slot
      __hip_atomic_store(&amax[(s+1)&1], 0ull, RLX, AGT);

    // ===== D: logits + packed argmax =====
    {
      for (int i = tid; i < JOINT_H; i += NTHR)               // FULL 640
        hsh[i] = __hip_atomic_load(&hid[i], RLX, AGT);
      __syncthreads();
      float accA = 0.f, accB = 0.f;
      #pragma unroll
      for (int i = 0; i < 10; ++i){
        float h = hsh[lane+(i<<6)];
        accA = fmaf(wj2A[i], h, accA);
        accB = fmaf(wj2B[i], h, accB);
      }
      accA = wave_red(accA);
      accB = wave_red(accB);
      if (lane == 0){
        float lgA = accA + bjA2, lgB = accB + bjB2;
        out[(size_t)s*VOCAB + rA2] = lgA;
        out[(size_t)s*VOCAB + rB2] = lgB;
        unsigned long long pA = packlg(lgA, rA2), pB = packlg(lgB, rB2);
        psh[wave] = pA > pB ? pA : pB;
      }
      __syncthreads();
      if (tid == 0){
        unsigned long long m = psh[0];
        #pragma unroll
        for (int w = 1; w < 8; ++w) if (psh[w] > m) m = psh[w];
        atomicMax(&amax[s&1], m);
      }
    }
    ep = gbar(wsb, ep, 1, amax, s&1, tid, wg, &ksh);   // fused: flag carries k
    int k = ksh;

    // ===== E: decision (replicated in every WG) =====
    bool stop = (k == 0) || (sa >= MAX_SYM);
    if (!stop){
      if (wg == 0 && tid == 0) out[(size_t)NSTEPS*VOCAB + cnt] = (float)k;
      if (tid < nj){ c0c[tid] = c0p[tid]; c1c[tid] = c1p[tid]; }
      cnt++; sa++; last = k; curb ^= 1;
    } else {
      sa = 0; t++;
      if (t >= timesteps) done = true;
    }
  }

  // labels tail (-1) and cnt
  size_t lab = (size_t)NSTEPS*VOCAB;
  int gidx = wg*NTHR + tid;
  for (int i = cnt + gidx; i < NSTEPS; i += NWG*NTHR) out[lab + i] = -1.f;
  if (wg == 0 && tid == 0) out[lab + NSTEPS] = (float)cnt;
}

extern "C" void kernel_launch(void* const* d_in, const int* in_sizes, int n_in,
                              void* d_out, int out_size, void* d_ws, size_t ws_size,
                              hipStream_t stream) {
  const float* enc  = (const float*)d_in[0];
  const int*   olen = (const int*)  d_in[1];
  const float* emb  = (const float*)d_in[2];
  const float* Wih0 = (const float*)d_in[3];
  const float* Whh0 = (const float*)d_in[4];
  const float* b0   = (const float*)d_in[5];
  const float* Wih1 = (const float*)d_in[6];
  const float* Whh1 = (const float*)d_in[7];
  const float* b1   = (const float*)d_in[8];
  const float* Wj1  = (const float*)d_in[9];
  const float* bj1  = (const float*)d_in[10];
  const float* Wj2  = (const float*)d_in[11];
  const float* bj2  = (const float*)d_in[12];
  float* out = (float*)d_out;

  unsigned* wsb = (unsigned*)d_ws;
  unsigned long long* amax = (unsigned long long*)((char*)d_ws + 2176);
  float* bufs = (float*)((char*)d_ws + 2240);
  float* hid  = (float*)((char*)d_ws + 12480);

  init_ws<<<1, 256, 0, stream>>>(wsb);

  void* args[] = {&enc,&olen,&emb,&Wih0,&Whh0,&b0,&Wih1,&Whh1,&b1,
                  &Wj1,&bj1,&Wj2,&bj2,&out,&wsb,&amax,&bufs,&hid};
  hipLaunchCooperativeKernel((const void*)rnnt_decode, dim3(NWG), dim3(NTHR),
                             args, 0, stream);
}

// Round 4
// 53443.805 us; speedup vs baseline: 11.7591x; 1.8890x over previous
//
#include <hip/hip_runtime.h>
#include <cmath>

#define VOCAB   4096
#define ENC_DIM 1024
#define PRED_H  640
#define JOINT_H 640
#define TMAX    128
#define MAX_SYM 30
#define NSTEPS  (TMAX*(MAX_SYM+1))   // 3968
#define NWG     256
#define NTHR    512
#define RLX __ATOMIC_RELAXED
#define AGT __HIP_MEMORY_SCOPE_AGENT

typedef unsigned long long u64;

// ws layout (bytes):
//   0     : bcast[8] u32, one per 64B line (8 clusters of 32 WGs)      [0,512)
//   512   : partials[256] u64 (tagged argmax entries)                  [512,2560)
//   4096  : bufsT: 2 x [h0(640)|h1(640)] tagged u64                    [4096,24576)
//   24576 : hidT[640] tagged u64                                       [24576,29696)
// tagged word = (epoch u32 << 32) | f32 bits.  epoch = s+1 (>=1; 0 = unwritten)

__device__ __forceinline__ float wave_red(float v){
  v += __shfl_xor(v, 32, 64);
  v += __shfl_xor(v, 16, 64);
  v += __shfl_xor(v,  8, 64);
  v += __shfl_xor(v,  4, 64);
  v += __shfl_xor(v,  2, 64);
  v += __shfl_xor(v,  1, 64);
  return v;
}

__device__ __forceinline__ float sigf(float x){ return 1.0f/(1.0f+expf(-x)); }

__device__ __forceinline__ void tstore(u64* p, float v, unsigned tag){
  __hip_atomic_store(p, ((u64)tag<<32) | (u64)__float_as_uint(v), RLX, AGT);
}
__device__ __forceinline__ float tpoll(u64* p, unsigned tag){
  u64 e = __hip_atomic_load(p, RLX, AGT);
  while ((unsigned)(e>>32) != tag){
    __builtin_amdgcn_s_sleep(1);
    e = __hip_atomic_load(p, RLX, AGT);
  }
  return __uint_as_float((unsigned)e);
}
__device__ __forceinline__ float tread(u64* p){   // previously-observed data: no tag check
  return __uint_as_float((unsigned)__hip_atomic_load(p, RLX, AGT));
}

// argmax entry: key(32b order-preserving float) << 24 | (ep&0xFFF)<<12 | (4095-r)
// same-epoch entries order by (key, 4095-r): max => largest logit, ties -> smallest r.
__device__ __forceinline__ u64 mkentry(float lg, int r, unsigned ep){
  unsigned u = __float_as_uint(lg);
  u = (u & 0x80000000u) ? ~u : (u | 0x80000000u);
  return ((u64)u<<24) | ((u64)(ep&0xFFFu)<<12) | (u64)(4095 - r);
}

__global__ void init_ws(unsigned* ws){
  for (int i = threadIdx.x; i < 8192; i += 256) ws[i] = 0u;   // 32 KB
}

__global__ __launch_bounds__(NTHR, 2)
void rnnt_decode(const float* __restrict__ enc,
                 const int*   __restrict__ outlen_p,
                 const float* __restrict__ emb,
                 const float* __restrict__ Wih0, const float* __restrict__ Whh0, const float* __restrict__ b0,
                 const float* __restrict__ Wih1, const float* __restrict__ Whh1, const float* __restrict__ b1,
                 const float* __restrict__ Wj1,  const float* __restrict__ bj1,
                 const float* __restrict__ Wj2,  const float* __restrict__ bj2,
                 float* __restrict__ out,
                 unsigned* __restrict__ bcast,   // [8] lines (stride 16 u32)
                 u64* __restrict__ parts,        // [256]
                 u64* __restrict__ bufsT,        // [2][2*PRED_H]
                 u64* __restrict__ hidT)         // [JOINT_H]
{
  const int wg = blockIdx.x, tid = threadIdx.x;
  const int wave = tid >> 6, lane = tid & 63;
  const int timesteps = outlen_p[0];

  __shared__ float xsh[ENC_DIM];
  __shared__ float hsh[PRED_H];
  __shared__ float zsh[4][4];
  __shared__ float zjs[8];
  __shared__ float c0c[4], c1c[4], c0p[4], c1p[4];
  __shared__ u64 psh[8];
  __shared__ int ksh;

  const int jb = (wg*PRED_H)/NWG;
  const int je = ((wg+1)*PRED_H)/NWG;
  const int nj = je - jb;                 // 2 or 3

  // ---- persistent weight registers (identical mapping to round-3) ----
  const int riA = wave, riB = wave + 8;
  const int gA = riA & 3, jA = riA >> 2;
  const int gB = riB & 3, jBx = riB >> 2;
  const bool hasB = (riB < 4*nj);
  const int rowA = gA*PRED_H + jb + jA;
  const int rowB = hasB ? (gB*PRED_H + jb + jBx) : 0;

  float w0xA[10], w0hA[10], w0xB[10], w0hB[10];
  float w1xA[10], w1hA[10], w1xB[10], w1hB[10];
  #pragma unroll
  for (int i = 0; i < 10; ++i){
    int c = lane + (i<<6);
    w0xA[i] = Wih0[(size_t)rowA*PRED_H + c];
    w0hA[i] = Whh0[(size_t)rowA*PRED_H + c];
    w1xA[i] = Wih1[(size_t)rowA*PRED_H + c];
    w1hA[i] = Whh1[(size_t)rowA*PRED_H + c];
    w0xB[i] = hasB ? Wih0[(size_t)rowB*PRED_H + c] : 0.f;
    w0hB[i] = hasB ? Whh0[(size_t)rowB*PRED_H + c] : 0.f;
    w1xB[i] = hasB ? Wih1[(size_t)rowB*PRED_H + c] : 0.f;
    w1hB[i] = hasB ? Whh1[(size_t)rowB*PRED_H + c] : 0.f;
  }
  const float bA0 = b0[rowA], bA1 = b1[rowA];
  const float bB0 = hasB ? b0[rowB] : 0.f, bB1 = hasB ? b1[rowB] : 0.f;

  float wj1f[3][4], wj1h[3][3];
  #pragma unroll
  for (int rr = 0; rr < 3; ++rr){
    #pragma unroll
    for (int i = 0; i < 4; ++i) wj1f[rr][i] = 0.f;
    #pragma unroll
    for (int i = 0; i < 3; ++i) wj1h[rr][i] = 0.f;
    if (rr < nj && tid < 256){
      int r = jb + rr;
      #pragma unroll
      for (int i = 0; i < 4; ++i)
        wj1f[rr][i] = Wj1[(size_t)r*(ENC_DIM+PRED_H) + tid + (i<<8)];
      #pragma unroll
      for (int i = 0; i < 3; ++i){
        int c = tid + (i<<8);
        wj1h[rr][i] = (c < PRED_H) ? Wj1[(size_t)r*(ENC_DIM+PRED_H) + ENC_DIM + c] : 0.f;
      }
    }
  }

  const int rA2 = wg*16 + wave*2, rB2 = rA2 + 1;
  float wj2A[10], wj2B[10];
  #pragma unroll
  for (int i = 0; i < 10; ++i){
    int c = lane + (i<<6);
    wj2A[i] = Wj2[(size_t)rA2*JOINT_H + c];
    wj2B[i] = Wj2[(size_t)rB2*JOINT_H + c];
  }
  const float bjA2 = bj2[rA2], bjB2 = bj2[rB2];

  if (tid < 4){ c0c[tid] = 0.f; c1c[tid] = 0.f; }
  __syncthreads();

  int curb = 0, t = 0, sa = 0, last = -1, cnt = 0;
  bool done = false;

  for (int s = 0; s < NSTEPS; ++s){
    if (done){
      if (wg < 8) out[(size_t)s*VOCAB + wg*NTHR + tid] = 0.f;
      continue;
    }
    const unsigned tag = (unsigned)(s + 1);
    u64* hcT = bufsT + curb*(2*PRED_H);
    u64* hpT = bufsT + (curb^1)*(2*PRED_H);

    // ===== A: LSTM layer 0 =====
    // hc data was tag-confirmed by THIS WG at the previous step's polls -> no tag check.
    for (int i = tid; i < PRED_H; i += NTHR){
      hsh[i] = tread(&hcT[i]);
      xsh[i] = (last >= 0) ? emb[(size_t)last*PRED_H + i] : 0.f;
    }
    __syncthreads();
    {
      float acc = 0.f;
      #pragma unroll
      for (int i = 0; i < 10; ++i) acc = fmaf(w0xA[i], xsh[lane+(i<<6)], acc);
      #pragma unroll
      for (int i = 0; i < 10; ++i) acc = fmaf(w0hA[i], hsh[lane+(i<<6)], acc);
      acc = wave_red(acc);
      if (lane == 0) zsh[gA][jA] = acc + bA0;
      if (hasB){
        float a2 = 0.f;
        #pragma unroll
        for (int i = 0; i < 10; ++i) a2 = fmaf(w0xB[i], xsh[lane+(i<<6)], a2);
        #pragma unroll
        for (int i = 0; i < 10; ++i) a2 = fmaf(w0hB[i], hsh[lane+(i<<6)], a2);
        a2 = wave_red(a2);
        if (lane == 0) zsh[gB][jBx] = a2 + bB0;
      }
    }
    __syncthreads();
    if (tid < nj){
      float ig = sigf(zsh[0][tid]), fg = sigf(zsh[1][tid]);
      float gg = tanhf(zsh[2][tid]), og = sigf(zsh[3][tid]);
      float c2 = fg*c0c[tid] + ig*gg;
      c0p[tid] = c2;
      tstore(&hpT[jb+tid], og*tanhf(c2), tag);    // release = the data store itself
    }
    __syncthreads();

    // ===== B: LSTM layer 1 =====
    for (int i = tid; i < PRED_H; i += NTHR){
      xsh[i] = tpoll(&hpT[i], tag);               // h0n (fresh: poll)
      hsh[i] = tread(&hcT[PRED_H+i]);             // h1 (observed earlier)
    }
    __syncthreads();
    {
      float acc = 0.f;
      #pragma unroll
      for (int i = 0; i < 10; ++i) acc = fmaf(w1xA[i], xsh[lane+(i<<6)], acc);
      #pragma unroll
      for (int i = 0; i < 10; ++i) acc = fmaf(w1hA[i], hsh[lane+(i<<6)], acc);
      acc = wave_red(acc);
      if (lane == 0) zsh[gA][jA] = acc + bA1;
      if (hasB){
        float a2 = 0.f;
        #pragma unroll
        for (int i = 0; i < 10; ++i) a2 = fmaf(w1xB[i], xsh[lane+(i<<6)], a2);
        #pragma unroll
        for (int i = 0; i < 10; ++i) a2 = fmaf(w1hB[i], hsh[lane+(i<<6)], a2);
        a2 = wave_red(a2);
        if (lane == 0) zsh[gB][jBx] = a2 + bB1;
      }
    }
    __syncthreads();
    if (tid < nj){
      float ig = sigf(zsh[0][tid]), fg = sigf(zsh[1][tid]);
      float gg = tanhf(zsh[2][tid]), og = sigf(zsh[3][tid]);
      float c2 = fg*c1c[tid] + ig*gg;
      c1p[tid] = c2;
      tstore(&hpT[PRED_H+jb+tid], og*tanhf(c2), tag);
    }
    __syncthreads();

    // ===== C: joint hidden =====
    {
      int tcap = (t < TMAX-1) ? t : (TMAX-1);
      for (int i = tid; i < PRED_H; i += NTHR)
        hsh[i] = tpoll(&hpT[PRED_H+i], tag);      // h1n (fresh: poll)
      for (int i = tid; i < ENC_DIM; i += NTHR)
        xsh[i] = enc[(size_t)tcap*ENC_DIM + i];
      __syncthreads();
      #pragma unroll
      for (int rr = 0; rr < 3; ++rr){
        if (rr < nj){
          if (tid < 256){
            float acc = 0.f;
            #pragma unroll
            for (int i = 0; i < 4; ++i) acc = fmaf(wj1f[rr][i], xsh[tid+(i<<8)], acc);
            #pragma unroll
            for (int i = 0; i < 3; ++i){
              int c = tid + (i<<8);
              acc = fmaf(wj1h[rr][i], hsh[(c < PRED_H) ? c : 0], acc);
            }
            acc = wave_red(acc);
            if (lane == 0) zjs[wave] = acc;
          }
          __syncthreads();
          if (tid == 0){
            float v = zjs[0] + zjs[1] + zjs[2] + zjs[3] + bj1[jb+rr];
            tstore(&hidT[jb+rr], v > 0.f ? v : 0.f, tag);
          }
          __syncthreads();
        }
      }
    }

    // ===== D: logits + tagged-tree argmax =====
    {
      for (int i = tid; i < JOINT_H; i += NTHR)
        hsh[i] = tpoll(&hidT[i], tag);            // hid (fresh: poll)
      __syncthreads();
      float accA = 0.f, accB = 0.f;
      #pragma unroll
      for (int i = 0; i < 10; ++i){
        float h = hsh[lane+(i<<6)];
        accA = fmaf(wj2A[i], h, accA);
        accB = fmaf(wj2B[i], h, accB);
      }
      accA = wave_red(accA);
      accB = wave_red(accB);
      if (lane == 0){
        float lgA = accA + bjA2, lgB = accB + bjB2;
        out[(size_t)s*VOCAB + rA2] = lgA;
        out[(size_t)s*VOCAB + rB2] = lgB;
        u64 eA = mkentry(lgA, rA2, tag), eB = mkentry(lgB, rB2, tag);
        psh[wave] = eA > eB ? eA : eB;
      }
      __syncthreads();
      if (tid == 0){
        u64 m = psh[0];
        #pragma unroll
        for (int w = 1; w < 8; ++w) if (psh[w] > m) m = psh[w];
        __hip_atomic_store(&parts[wg], m, RLX, AGT);
      }
      // wg0/wave0: reduce all 256 partials, broadcast k to 8 cluster lines
      if (wg == 0 && wave == 0){
        u64 m = 0;
        #pragma unroll
        for (int q = 0; q < 4; ++q){
          int idx = lane + (q<<6);
          u64 e = __hip_atomic_load(&parts[idx], RLX, AGT);
          while ((unsigned)((e>>12) & 0xFFFu) != (tag & 0xFFFu)){
            __builtin_amdgcn_s_sleep(1);
            e = __hip_atomic_load(&parts[idx], RLX, AGT);
          }
          if (e > m) m = e;
        }
        #pragma unroll
        for (int off = 32; off; off >>= 1){
          u64 o = __shfl_xor(m, off, 64);
          if (o > m) m = o;
        }
        int kk = 4095 - (int)(m & 0xFFFull);
        if (lane < 8)
          __hip_atomic_store(&bcast[lane*16], (tag<<12) | (unsigned)kk, RLX, AGT);
        if (lane == 0) ksh = kk;
      } else if (tid == 0){
        unsigned f = __hip_atomic_load(&bcast[(wg>>5)*16], RLX, AGT);
        while ((f >> 12) != tag){
          __builtin_amdgcn_s_sleep(1);
          f = __hip_atomic_load(&bcast[(wg>>5)*16], RLX, AGT);
        }
        ksh = (int)(f & 0xFFFu);
      }
      __syncthreads();
    }
    int k = ksh;
    __syncthreads();

    // ===== E: decision (replicated) =====
    bool stop = (k == 0) || (sa >= MAX_SYM);
    if (!stop){
      if (wg == 0 && tid == 0) out[(size_t)NSTEPS*VOCAB + cnt] = (float)k;
      if (tid < nj){ c0c[tid] = c0p[tid]; c1c[tid] = c1p[tid]; }
      cnt++; sa++; last = k; curb ^= 1;
    } else {
      sa = 0; t++;
      if (t >= timesteps) done = true;
    }
  }

  // labels tail (-1) and cnt
  size_t lab = (size_t)NSTEPS*VOCAB;
  int gidx = wg*NTHR + tid;
  for (int i = cnt + gidx; i < NSTEPS; i += NWG*NTHR) out[lab + i] = -1.f;
  if (wg == 0 && tid == 0) out[lab + NSTEPS] = (float)cnt;
}

extern "C" void kernel_launch(void* const* d_in, const int* in_sizes, int n_in,
                              void* d_out, int out_size, void* d_ws, size_t ws_size,
                              hipStream_t stream) {
  const float* enc  = (const float*)d_in[0];
  const int*   olen = (const int*)  d_in[1];
  const float* emb  = (const float*)d_in[2];
  const float* Wih0 = (const float*)d_in[3];
  const float* Whh0 = (const float*)d_in[4];
  const float* b0   = (const float*)d_in[5];
  const float* Wih1 = (const float*)d_in[6];
  const float* Whh1 = (const float*)d_in[7];
  const float* b1   = (const float*)d_in[8];
  const float* Wj1  = (const float*)d_in[9];
  const float* bj1  = (const float*)d_in[10];
  const float* Wj2  = (const float*)d_in[11];
  const float* bj2  = (const float*)d_in[12];
  float* out = (float*)d_out;

  unsigned* bcast = (unsigned*)d_ws;
  u64* parts = (u64*)((char*)d_ws + 512);
  u64* bufsT = (u64*)((char*)d_ws + 4096);
  u64* hidT  = (u64*)((char*)d_ws + 24576);

  init_ws<<<1, 256, 0, stream>>>((unsigned*)d_ws);

  void* args[] = {&enc,&olen,&emb,&Wih0,&Whh0,&b0,&Wih1,&Whh1,&b1,
                  &Wj1,&bj1,&Wj2,&bj2,&out,&bcast,&parts,&bufsT,&hidT};
  hipLaunchCooperativeKernel((const void*)rnnt_decode, dim3(NWG), dim3(NTHR),
                             args, 0, stream);
}

// Round 5
// 51190.903 us; speedup vs baseline: 12.2766x; 1.0440x over previous
//
#include <hip/hip_runtime.h>
#include <cmath>

#define VOCAB   4096
#define ENC_DIM 1024
#define PRED_H  640
#define JOINT_H 640
#define TMAX    128
#define MAX_SYM 30
#define NSTEPS  (TMAX*(MAX_SYM+1))   // 3968
#define NWG     256
#define NTHR    512
#define RLX __ATOMIC_RELAXED
#define AGT __HIP_MEMORY_SCOPE_AGENT

typedef unsigned long long u64;

// ws layout (bytes):
//   0     : parts[256] u64 (tagged argmax entries)        [0,2048)
//   4096  : bufsT[1280] u64: h0n(640) | h1n(640) tagged   [4096,14336)
//   16384 : hidT[640] u64 tagged                          [16384,21504)
// tagged word = (tag u32 << 32) | f32 bits. tag = s+1 (>=1; 0 = unwritten)

__device__ __forceinline__ float wave_red(float v){
  v += __shfl_xor(v, 32, 64);
  v += __shfl_xor(v, 16, 64);
  v += __shfl_xor(v,  8, 64);
  v += __shfl_xor(v,  4, 64);
  v += __shfl_xor(v,  2, 64);
  v += __shfl_xor(v,  1, 64);
  return v;
}

__device__ __forceinline__ float sigf(float x){ return 1.0f/(1.0f+expf(-x)); }

__device__ __forceinline__ void tstore(u64* p, float v, unsigned tag){
  __hip_atomic_store(p, ((u64)tag<<32) | (u64)__float_as_uint(v), RLX, AGT);
}
__device__ __forceinline__ float tpollv(u64* p, unsigned tag){
  u64 e = __hip_atomic_load(p, RLX, AGT);
  while ((unsigned)(e>>32) != tag){
    __builtin_amdgcn_s_sleep(4);
    e = __hip_atomic_load(p, RLX, AGT);
  }
  return __uint_as_float((unsigned)e);
}

// argmax entry: key(32b order-preserving) << 24 | (tag&0xFFF)<<12 | (4095-r)
__device__ __forceinline__ u64 mkentry(float lg, int r, unsigned ep){
  unsigned u = __float_as_uint(lg);
  u = (u & 0x80000000u) ? ~u : (u | 0x80000000u);
  return ((u64)u<<24) | ((u64)(ep&0xFFFu)<<12) | (u64)(4095 - r);
}

__global__ void init_ws(unsigned* ws){
  for (int i = threadIdx.x; i < 8192; i += 256) ws[i] = 0u;   // 32 KB
}

__global__ __launch_bounds__(NTHR, 2)
void rnnt_decode(const float* __restrict__ enc,
                 const int*   __restrict__ outlen_p,
                 const float* __restrict__ emb,
                 const float* __restrict__ Wih0, const float* __restrict__ Whh0, const float* __restrict__ b0,
                 const float* __restrict__ Wih1, const float* __restrict__ Whh1, const float* __restrict__ b1,
                 const float* __restrict__ Wj1,  const float* __restrict__ bj1,
                 const float* __restrict__ Wj2,  const float* __restrict__ bj2,
                 float* __restrict__ out,
                 u64* __restrict__ parts,        // [256]
                 u64* __restrict__ bufsT,        // [2*PRED_H]
                 u64* __restrict__ hidT)         // [JOINT_H]
{
  const int wg = blockIdx.x, tid = threadIdx.x;
  const int wave = tid >> 6, lane = tid & 63;
  const int timesteps = outlen_p[0];

  __shared__ float xa[PRED_H];            // embedding input
  __shared__ float xsh[ENC_DIM];          // enc frame (persists across same-t steps)
  __shared__ float h0buf[2][PRED_H];      // current / proposal h0
  __shared__ float h1buf[2][PRED_H];      // current / proposal h1
  __shared__ float hidsh[JOINT_H];
  __shared__ float zsh[4][4];
  __shared__ float zjs[8];
  __shared__ float c0c[4], c1c[4], c0p[4], c1p[4];
  __shared__ u64 psh[8];
  __shared__ u64 pmx[4];

  const int jb = (wg*PRED_H)/NWG;
  const int je = ((wg+1)*PRED_H)/NWG;
  const int nj = je - jb;                 // 2 or 3

  // ---- persistent LSTM weight registers (identical mapping to R4) ----
  const int riA = wave, riB = wave + 8;
  const int gA = riA & 3, jA = riA >> 2;
  const int gB = riB & 3, jBx = riB >> 2;
  const bool hasB = (riB < 4*nj);
  const int rowA = gA*PRED_H + jb + jA;
  const int rowB = hasB ? (gB*PRED_H + jb + jBx) : 0;

  float w0xA[10], w0hA[10], w0xB[10], w0hB[10];
  float w1xA[10], w1hA[10], w1xB[10], w1hB[10];
  #pragma unroll
  for (int i = 0; i < 10; ++i){
    int c = lane + (i<<6);
    w0xA[i] = Wih0[(size_t)rowA*PRED_H + c];
    w0hA[i] = Whh0[(size_t)rowA*PRED_H + c];
    w1xA[i] = Wih1[(size_t)rowA*PRED_H + c];
    w1hA[i] = Whh1[(size_t)rowA*PRED_H + c];
    w0xB[i] = hasB ? Wih0[(size_t)rowB*PRED_H + c] : 0.f;
    w0hB[i] = hasB ? Whh0[(size_t)rowB*PRED_H + c] : 0.f;
    w1xB[i] = hasB ? Wih1[(size_t)rowB*PRED_H + c] : 0.f;
    w1hB[i] = hasB ? Whh1[(size_t)rowB*PRED_H + c] : 0.f;
  }
  const float bA0 = b0[rowA], bA1 = b1[rowA];
  const float bB0 = hasB ? b0[rowB] : 0.f, bB1 = hasB ? b1[rowB] : 0.f;

  // ---- Wj1 per-role (waves 0-3: rows jb, jb+2; waves 4-7: row jb+1) ----
  const int vt = (wave < 4) ? wave*64 + lane : (wave-4)*64 + lane;  // virtual tid 0..255
  float wjf0[4], wjh0[3], wjf2[4], wjh2[3];
  {
    int r0 = (wave < 4) ? jb : jb + 1;
    #pragma unroll
    for (int i = 0; i < 4; ++i) wjf0[i] = Wj1[(size_t)r0*(ENC_DIM+PRED_H) + vt + (i<<8)];
    #pragma unroll
    for (int i = 0; i < 3; ++i){
      int c = vt + (i<<8);
      wjh0[i] = (c < PRED_H) ? Wj1[(size_t)r0*(ENC_DIM+PRED_H) + ENC_DIM + c] : 0.f;
    }
    #pragma unroll
    for (int i = 0; i < 4; ++i) wjf2[i] = 0.f;
    #pragma unroll
    for (int i = 0; i < 3; ++i) wjh2[i] = 0.f;
    if (wave < 4 && nj == 3){
      int r2 = jb + 2;
      #pragma unroll
      for (int i = 0; i < 4; ++i) wjf2[i] = Wj1[(size_t)r2*(ENC_DIM+PRED_H) + vt + (i<<8)];
      #pragma unroll
      for (int i = 0; i < 3; ++i){
        int c = vt + (i<<8);
        wjh2[i] = (c < PRED_H) ? Wj1[(size_t)r2*(ENC_DIM+PRED_H) + ENC_DIM + c] : 0.f;
      }
    }
  }
  float bjr[3];
  bjr[0] = bj1[jb]; bjr[1] = bj1[jb+1]; bjr[2] = (nj == 3) ? bj1[jb+2] : 0.f;
  float ca0 = 0.f, ca2 = 0.f;             // cached f-part chain results

  // ---- Wj2: 16 rows per WG, 2 per wave ----
  const int rA2 = wg*16 + wave*2, rB2 = rA2 + 1;
  float wj2A[10], wj2B[10];
  #pragma unroll
  for (int i = 0; i < 10; ++i){
    int c = lane + (i<<6);
    wj2A[i] = Wj2[(size_t)rA2*JOINT_H + c];
    wj2B[i] = Wj2[(size_t)rB2*JOINT_H + c];
  }
  const float bjA2 = bj2[rA2], bjB2 = bj2[rB2];

  for (int i = tid; i < PRED_H; i += NTHR){ h0buf[0][i] = 0.f; h1buf[0][i] = 0.f; }
  if (tid < 4){ c0c[tid] = 0.f; c1c[tid] = 0.f; }
  __syncthreads();

  int cur = 0, t = 0, sa = 0, last = -1, cnt = 0, tStaged = -1;
  bool done = false, reuse = false;

  for (int s = 0; s < NSTEPS; ++s){
    if (done){
      if (wg < 8) out[(size_t)s*VOCAB + wg*NTHR + tid] = 0.f;
      continue;
    }
    const unsigned tag = (unsigned)(s + 1);

    if (!reuse){
      // ===== A: LSTM layer 0 (all inputs LDS-local) =====
      for (int i = tid; i < PRED_H; i += NTHR)
        xa[i] = (last >= 0) ? emb[(size_t)last*PRED_H + i] : 0.f;
      __syncthreads();
      {
        float acc = 0.f;
        #pragma unroll
        for (int i = 0; i < 10; ++i) acc = fmaf(w0xA[i], xa[lane+(i<<6)], acc);
        #pragma unroll
        for (int i = 0; i < 10; ++i) acc = fmaf(w0hA[i], h0buf[cur][lane+(i<<6)], acc);
        acc = wave_red(acc);
        if (lane == 0) zsh[gA][jA] = acc + bA0;
        if (hasB){
          float a2 = 0.f;
          #pragma unroll
          for (int i = 0; i < 10; ++i) a2 = fmaf(w0xB[i], xa[lane+(i<<6)], a2);
          #pragma unroll
          for (int i = 0; i < 10; ++i) a2 = fmaf(w0hB[i], h0buf[cur][lane+(i<<6)], a2);
          a2 = wave_red(a2);
          if (lane == 0) zsh[gB][jBx] = a2 + bB0;
        }
      }
      __syncthreads();
      if (tid < nj){
        float ig = sigf(zsh[0][tid]), fg = sigf(zsh[1][tid]);
        float gg = tanhf(zsh[2][tid]), og = sigf(zsh[3][tid]);
        float c2 = fg*c0c[tid] + ig*gg;
        c0p[tid] = c2;
        tstore(&bufsT[jb+tid], og*tanhf(c2), tag);
      }
      __syncthreads();

      // ===== B: LSTM layer 1 =====
      for (int i = tid; i < PRED_H; i += NTHR)
        h0buf[cur^1][i] = tpollv(&bufsT[i], tag);          // h0n (1 RTT)
      __syncthreads();
      {
        float acc = 0.f;
        #pragma unroll
        for (int i = 0; i < 10; ++i) acc = fmaf(w1xA[i], h0buf[cur^1][lane+(i<<6)], acc);
        #pragma unroll
        for (int i = 0; i < 10; ++i) acc = fmaf(w1hA[i], h1buf[cur][lane+(i<<6)], acc);
        acc = wave_red(acc);
        if (lane == 0) zsh[gA][jA] = acc + bA1;
        if (hasB){
          float a2 = 0.f;
          #pragma unroll
          for (int i = 0; i < 10; ++i) a2 = fmaf(w1xB[i], h0buf[cur^1][lane+(i<<6)], a2);
          #pragma unroll
          for (int i = 0; i < 10; ++i) a2 = fmaf(w1hB[i], h1buf[cur][lane+(i<<6)], a2);
          a2 = wave_red(a2);
          if (lane == 0) zsh[gB][jBx] = a2 + bB1;
        }
      }
      __syncthreads();
      if (tid < nj){
        float ig = sigf(zsh[0][tid]), fg = sigf(zsh[1][tid]);
        float gg = tanhf(zsh[2][tid]), og = sigf(zsh[3][tid]);
        float c2 = fg*c1c[tid] + ig*gg;
        c1p[tid] = c2;
        tstore(&bufsT[PRED_H+jb+tid], og*tanhf(c2), tag);
      }
      // no barrier needed before C's poll staging (poll self-synchronizes)
    }

    // ===== C: joint hidden =====
    {
      int tcap = (t < TMAX-1) ? t : (TMAX-1);
      bool fNew = (tcap != tStaged);
      if (fNew)
        for (int i = tid; i < ENC_DIM; i += NTHR) xsh[i] = enc[(size_t)tcap*ENC_DIM + i];
      if (!reuse)
        for (int i = tid; i < PRED_H; i += NTHR)
          h1buf[cur^1][i] = tpollv(&bufsT[PRED_H+i], tag);  // h1n (1 RTT)
      __syncthreads();
      if (fNew){
        float a = 0.f;
        #pragma unroll
        for (int i = 0; i < 4; ++i) a = fmaf(wjf0[i], xsh[vt+(i<<8)], a);
        ca0 = a;
        if (wave < 4 && nj == 3){
          float a2 = 0.f;
          #pragma unroll
          for (int i = 0; i < 4; ++i) a2 = fmaf(wjf2[i], xsh[vt+(i<<8)], a2);
          ca2 = a2;
        }
        tStaged = tcap;
      }
      {
        float acc = ca0;                                    // exact chain prefix
        #pragma unroll
        for (int i = 0; i < 3; ++i){
          int c = vt + (i<<8);
          acc = fmaf(wjh0[i], h1buf[cur^1][(c < PRED_H) ? c : 0], acc);
        }
        acc = wave_red(acc);
        if (lane == 0) zjs[wave] = acc;
      }
      __syncthreads();
      if (tid == 0){
        float v0 = zjs[0]+zjs[1]+zjs[2]+zjs[3] + bjr[0];
        tstore(&hidT[jb],   v0 > 0.f ? v0 : 0.f, tag);
        float v1 = zjs[4]+zjs[5]+zjs[6]+zjs[7] + bjr[1];
        tstore(&hidT[jb+1], v1 > 0.f ? v1 : 0.f, tag);
      }
      if (nj == 3){
        __syncthreads();
        if (wave < 4){
          float acc = ca2;
          #pragma unroll
          for (int i = 0; i < 3; ++i){
            int c = vt + (i<<8);
            acc = fmaf(wjh2[i], h1buf[cur^1][(c < PRED_H) ? c : 0], acc);
          }
          acc = wave_red(acc);
          if (lane == 0) zjs[wave] = acc;
        }
        __syncthreads();
        if (tid == 0){
          float v2 = zjs[0]+zjs[1]+zjs[2]+zjs[3] + bjr[2];
          tstore(&hidT[jb+2], v2 > 0.f ? v2 : 0.f, tag);
        }
      }
    }

    // ===== D: logits + argmax (parts all-gather, no bcast hop) =====
    int k;
    {
      for (int i = tid; i < JOINT_H; i += NTHR)
        hidsh[i] = tpollv(&hidT[i], tag);                   // hid (1 RTT)
      __syncthreads();
      float accA = 0.f, accB = 0.f;
      #pragma unroll
      for (int i = 0; i < 10; ++i){
        float h = hidsh[lane+(i<<6)];
        accA = fmaf(wj2A[i], h, accA);
        accB = fmaf(wj2B[i], h, accB);
      }
      accA = wave_red(accA);
      accB = wave_red(accB);
      if (lane == 0){
        float lgA = accA + bjA2, lgB = accB + bjB2;
        out[(size_t)s*VOCAB + rA2] = lgA;
        out[(size_t)s*VOCAB + rB2] = lgB;
        u64 eA = mkentry(lgA, rA2, tag), eB = mkentry(lgB, rB2, tag);
        psh[wave] = eA > eB ? eA : eB;
      }
      __syncthreads();
      if (tid == 0){
        u64 m = psh[0];
        #pragma unroll
        for (int w = 1; w < 8; ++w) if (psh[w] > m) m = psh[w];
        __hip_atomic_store(&parts[wg], m, RLX, AGT);
      }
      // all-WG gather of 256 partials (1 RTT), local reduce
      u64 myp = 0;
      if (tid < 256){
        u64 e = __hip_atomic_load(&parts[tid], RLX, AGT);
        while ((unsigned)((e>>12) & 0xFFFu) != (tag & 0xFFFu)){
          __builtin_amdgcn_s_sleep(2);
          e = __hip_atomic_load(&parts[tid], RLX, AGT);
        }
        myp = e;
      }
      if (wave < 4){
        #pragma unroll
        for (int off = 32; off; off >>= 1){
          u64 o = __shfl_xor(myp, off, 64);
          if (o > myp) myp = o;
        }
        if (lane == 0) pmx[wave] = myp;
      }
      __syncthreads();
      u64 m = pmx[0];
      if (pmx[1] > m) m = pmx[1];
      if (pmx[2] > m) m = pmx[2];
      if (pmx[3] > m) m = pmx[3];
      k = 4095 - (int)(m & 0xFFFull);
    }

    // ===== E: decision (replicated in every WG) =====
    bool stop = (k == 0) || (sa >= MAX_SYM);
    if (!stop){
      if (wg == 0 && tid == 0) out[(size_t)NSTEPS*VOCAB + cnt] = (float)k;
      if (tid < nj){ c0c[tid] = c0p[tid]; c1c[tid] = c1p[tid]; }
      cnt++; sa++; last = k; cur ^= 1; reuse = false;
    } else {
      sa = 0; t++; reuse = true;
      if (t >= timesteps) done = true;
    }
    __syncthreads();
  }

  // labels tail (-1) and cnt
  size_t lab = (size_t)NSTEPS*VOCAB;
  int gidx = wg*NTHR + tid;
  for (int i = cnt + gidx; i < NSTEPS; i += NWG*NTHR) out[lab + i] = -1.f;
  if (wg == 0 && tid == 0) out[lab + NSTEPS] = (float)cnt;
}

extern "C" void kernel_launch(void* const* d_in, const int* in_sizes, int n_in,
                              void* d_out, int out_size, void* d_ws, size_t ws_size,
                              hipStream_t stream) {
  const float* enc  = (const float*)d_in[0];
  const int*   olen = (const int*)  d_in[1];
  const float* emb  = (const float*)d_in[2];
  const float* Wih0 = (const float*)d_in[3];
  const float* Whh0 = (const float*)d_in[4];
  const float* b0   = (const float*)d_in[5];
  const float* Wih1 = (const float*)d_in[6];
  const float* Whh1 = (const float*)d_in[7];
  const float* b1   = (const float*)d_in[8];
  const float* Wj1  = (const float*)d_in[9];
  const float* bj1  = (const float*)d_in[10];
  const float* Wj2  = (const float*)d_in[11];
  const float* bj2  = (const float*)d_in[12];
  float* out = (float*)d_out;

  u64* parts = (u64*)d_ws;
  u64* bufsT = (u64*)((char*)d_ws + 4096);
  u64* hidT  = (u64*)((char*)d_ws + 16384);

  init_ws<<<1, 256, 0, stream>>>((unsigned*)d_ws);

  void* args[] = {&enc,&olen,&emb,&Wih0,&Whh0,&b0,&Wih1,&Whh1,&b1,
                  &Wj1,&bj1,&Wj2,&bj2,&out,&parts,&bufsT,&hidT};
  hipLaunchCooperativeKernel((const void*)rnnt_decode, dim3(NWG), dim3(NTHR),
                             args, 0, stream);
}